// Round 25
// baseline (49.057 us; speedup 1.0000x reference)
//
#include <hip/hip_runtime.h>
#include <math.h>

// BipolarMorphological2D SMorph — fully fused single-kernel bf16 MFMA (R25).
// delta-form: e^kf = 1 + delta -> d = S_m + GEMM(m,delta); n = S_mlm + GEMM(..)
// |kf| <= 0.0833 -> expm1(k), k*e^k are 3-term Taylor polys (err 2e-6 << bf16)
// -> B-slice computed per block with NO transcendentals. Block (bm,nq) =
// 16 s x 64 N-cols: A-tile (36.9KB frag order, R16-verified) staged from x
// with exact fp32 window-sum partials accumulated on the side; B-slice
// (73.7KB frag order) from k1/k2 + Taylor; MFMA from LDS (lane-linear
// ds_read_b128); K-split-2 LDS combine + epilogue. 900 blocks x 512 thr
// (8 waves: kq2 x msub2 x nsplit2), 115KB LDS, 1 block/CU. ONE dispatch:
// no inter-kernel drain, no cross-XCD L3 round-trip of staged tables.

typedef float  f32x4 __attribute__((ext_vector_type(4)));
typedef short  s16x8 __attribute__((ext_vector_type(8)));

#define OO   64
#define WO   30
#define NSP  900

__device__ __forceinline__ unsigned short f2bf(float f) {
    unsigned u = __float_as_uint(f);
    return (unsigned short)((u + 0x7FFFu + ((u >> 16) & 1u)) >> 16);
}

// grid: 900 = 225 bm x 4 nq. 512 thr = 8 waves: kq = w>>2, msub = (w>>1)&1, nsplit = w&1.
__global__ __launch_bounds__(512, 1) void smorph_one(
    const float* __restrict__ x, const float* __restrict__ k1,
    const float* __restrict__ k2, const float* __restrict__ bias,
    float* __restrict__ out)
{
    __shared__ __align__(16) uint4 ldsA4[2304];       // 36,864 B  A-tile (frag order)
    __shared__ __align__(16) uint4 ldsB4[4*18*64];    // 73,728 B  B-slice (frag order)
    __shared__ float Sred[32*16*2];                   // 4 KB   S partials [g][sub][2]
    __shared__ float Sg[64];                          // reduced S [g][2]

    const int tid = threadIdx.x;
    const int bm  = blockIdx.x >> 2;
    const int nq  = blockIdx.x & 3;

    // ================= A staging (R16-verified indexing) + fp32 S partials =====
    float psm = 0.f, psl = 0.f;
    for (int u = tid; u < 2304; u += 512) {
        const int st  = u >> 7, r2 = u & 127;
        const int mi  = r2 >> 6, l2 = r2 & 63;
        const int lr2 = l2 & 15, lg2 = l2 >> 4;
        const int s    = bm*16 + mi*8 + (lr2 >> 1);
        const int sign = lr2 & 1;
        const int pos  = st >> 1, khalf = st & 1;
        const int kh   = pos/3, kw = pos - 3*(pos/3);
        const int b    = s / NSP, r = s - b*NSP;
        const int ho   = r / WO,  wo = r - WO*(r/WO);
        const int base = b*32768 + (ho + kh)*32 + (wo + kw);
        const int c0   = khalf*16 + lg2*4;
        unsigned pk[4];
#pragma unroll
        for (int q = 0; q < 4; ++q) {
            float v  = x[base + (c0 + q)*1024];
            float m  = sign ? fmaxf(-v, 0.1f) : fmaxf(v, 0.1f);
            float ml = m * __logf(m);
            psm += m; psl += ml;
            pk[q] = (unsigned)f2bf(m) | ((unsigned)f2bf(ml) << 16);
        }
        ldsA4[u] = make_uint4(pk[0], pk[1], pk[2], pk[3]);
    }
    {   // per-thread (g,sub) slot is bijective over tid's 9 bits
        const int g   = ((tid >> 6) & 1)*16 + (tid & 15);
        const int sub = (tid >> 7)*4 + ((tid >> 4) & 3);
        Sred[(g*16 + sub)*2 + 0] = psm;
        Sred[(g*16 + sub)*2 + 1] = psl;
    }

    // ================= B staging: Taylor, frag order, b128 writes =============
#pragma unroll
    for (int j = 0; j < 9; ++j) {
        const int t3  = tid + 512*j;          // 4608 items: (o_local, tbl, p-quad)
        const int ol  = t3 & 15;
        const int tbl = (t3 >> 4) & 3;
        const int p4  = t3 >> 6;              // 0..71
        const int o   = nq*16 + ol;
        const int st  = p4 >> 2;
        const int nl  = ol*4 + tbl;           // n_local 0..63
        const int lane = (nl & 15) + ((p4 & 3) << 4);
        const int ngl  = nl >> 4;
        unsigned wds[4];
#pragma unroll
        for (int pp = 0; pp < 4; ++pp) {
            const int p = p4*4 + pp;
            float a  = k1[p*64 + o], bb = k2[p*64 + o];
            float a2 = a*a,  b2 = bb*bb;
            float d1 = fmaf(a2, fmaf(a,  1.f/6.f, 0.5f), a);    // expm1(a)
            float q1 = fmaf(a2, fmaf(a,  0.5f,    1.f ), a);    // a*e^a
            float d2 = fmaf(b2, fmaf(bb, 1.f/6.f, 0.5f), bb);
            float q2 = fmaf(b2, fmaf(bb, 0.5f,    1.f ), bb);
            float v0 = (tbl == 0) ? d1 : (tbl == 1) ? q1 : (tbl == 2) ? d2 : q2;
            float v1 = (tbl == 1) ? d1 : (tbl == 3) ? d2 : 0.f;
            wds[pp] = (unsigned)f2bf(v0) | ((unsigned)f2bf(v1) << 16);
        }
        ldsB4[(ngl*18 + st)*64 + lane] = make_uint4(wds[0], wds[1], wds[2], wds[3]);
    }
    __syncthreads();   // A, B, Sred staged

    // ---- S reduce (wave 0): Sg[g*2+v] = sum over 16 subs
    if (tid < 64) {
        const int g = tid >> 1, v = tid & 1;
        float ssum = 0.f;
#pragma unroll
        for (int q = 0; q < 16; ++q) ssum += Sred[(g*16 + q)*2 + v];
        Sg[tid] = ssum;
    }

    // ================= MFMA: wave = 16M x 32N x 9 steps =======================
    const int l  = tid & 63;
    const int w  = tid >> 6;
    const int kq = w >> 2, msub = (w >> 1) & 1, nsplit = w & 1;
    const int lr = l & 15, lg = l >> 4;

    f32x4 acc[2] = {};
#pragma unroll
    for (int s2 = 0; s2 < 9; ++s2) {
        const int step = s2*2 + kq;
        s16x8 a  = *(const s16x8*)&ldsA4[step*128 + msub*64 + l];
        s16x8 b0 = *(const s16x8*)&ldsB4[((nsplit*2 + 0)*18 + step)*64 + l];
        s16x8 b1 = *(const s16x8*)&ldsB4[((nsplit*2 + 1)*18 + step)*64 + l];
        acc[0] = __builtin_amdgcn_mfma_f32_16x16x32_bf16(a, b0, acc[0], 0, 0, 0);
        acc[1] = __builtin_amdgcn_mfma_f32_16x16x32_bf16(a, b1, acc[1], 0, 0, 0);
    }
    __syncthreads();   // all A/B LDS reads done; A region reusable

    float* cmb = (float*)ldsA4;          // 2048 floats (8 KB)
    float* epi = (float*)ldsA4 + 2048;   // 2112 floats (32 x 66)

    // ---- K-combine: kq1 -> cmb[(msub,nsplit)], kq0 adds
    if (kq == 1) {
        float* dst = cmb + (msub*2 + nsplit)*512 + l;
#pragma unroll
        for (int ni = 0; ni < 2; ++ni)
#pragma unroll
            for (int r = 0; r < 4; ++r)
                dst[(ni*4 + r)*64] = acc[ni][r];
    }
    __syncthreads();
    if (kq == 0) {
        const float* srcp = cmb + (msub*2 + nsplit)*512 + l;
#pragma unroll
        for (int ni = 0; ni < 2; ++ni)
#pragma unroll
            for (int r = 0; r < 4; ++r)
                acc[ni][r] += srcp[(ni*4 + r)*64];

        // epilogue write: rows msub*16 + lg*4 + r, cols (nsplit*2+ni)*16 + lr
        const int wrbase = (msub*16 + lg*4)*66 + lr;
#pragma unroll
        for (int ni = 0; ni < 2; ++ni)
#pragma unroll
            for (int r = 0; r < 4; ++r)
                epi[wrbase + r*66 + (nsplit*2 + ni)*16] = acc[ni][r];
    }
    __syncthreads();

    // ---- final transform + store: 4 kq0 waves = 256 lanes = 16 s x 16 o
    if (kq == 0) {
        const int lgid = w*64 + l;            // 0..255
        const int sl = lgid >> 4, od = lgid & 15;
        const int s  = bm*16 + sl;
        const int b  = s / NSP, r900 = s - b*NSP;
        const int o  = nq*16 + od;
        float4 v0 = *(const float4*)&epi[(2*sl + 0)*66 + od*4];  // pos: d1,n1,d2,n2
        float4 v1 = *(const float4*)&epi[(2*sl + 1)*66 + od*4];  // neg
        const float Smp = Sg[(2*sl + 0)*2 + 0], Slp = Sg[(2*sl + 0)*2 + 1];
        const float Smn = Sg[(2*sl + 1)*2 + 0], Sln = Sg[(2*sl + 1)*2 + 1];
        float d1p = Smp + v0.x, n1p = Slp + v0.y;
        float d2p = Smp + v0.z, n2p = Slp + v0.w;
        float d1n = Smn + v1.x, n1n = Sln + v1.y;
        float d2n = Smn + v1.z, n2n = Sln + v1.w;
        float P = __expf(n1p/d1p) - __expf(n2p/d2p)
                - __expf(n1n/d1n) + __expf(n2n/d2n);
        out[((size_t)(b*OO + o))*NSP + r900] = P + bias[o];
    }
}

extern "C" void kernel_launch(void* const* d_in, const int* in_sizes, int n_in,
                              void* d_out, int out_size, void* d_ws, size_t ws_size,
                              hipStream_t stream) {
    const float* x    = (const float*)d_in[0];
    const float* k1   = (const float*)d_in[1];
    const float* k2   = (const float*)d_in[2];
    const float* bias = (const float*)d_in[3];
    float*       outp = (float*)d_out;

    hipLaunchKernelGGL(smorph_one, dim3(900), dim3(512), 0, stream,
                       x, k1, k2, bias, outp);
}

// Round 26
// 19.131 us; speedup vs baseline: 2.5642x; 2.5642x over previous
//
#include <hip/hip_runtime.h>
#include <math.h>

// BipolarMorphological2D SMorph as a bf16 MFMA GEMM (R26 = R23 + XCD swizzle).
// delta-form: e^kf = 1 + delta -> d = S_m + GEMM(m,delta); n = S_mlm + GEMM(..)
//   M = 7200 (s*2+sign), N = 256 (o*4+tbl), K = 576 (c*2+{m,mlm} per 3x3 pos)
// R26 change: bijective XCD-aware swizzle of gemm blockIdx (m204 form, since
// 900 % 8 != 0): each XCD gets a contiguous bm-range -> pixm/bt L3->L2
// warmup not repeated 8x, neighboring-bm A rows share an L2.
// Everything else = R23 best (19.56us): coalesced LDS-transpose prep,
// unique pixm table, frag-packed B, 450x(4-wave kq2 x nhf2) gemm, K-split-2.

typedef float  f32x4 __attribute__((ext_vector_type(4)));
typedef short  s16x8 __attribute__((ext_vector_type(8)));

#define BB   4
#define CC   32
#define HH   32
#define WW   32
#define OO   64
#define HO   30
#define WO   30
#define NSP  900
#define KDIM 576
#define TB   18432             // B-pack items
#define NWG  900               // gemm grid (450 handled as 900/2 pairs? no: 450)

__device__ __forceinline__ unsigned short f2bf(float f) {
    unsigned u = __float_as_uint(f);
    return (unsigned short)((u + 0x7FFFu + ((u >> 16) & 1u)) >> 16);
}

// ---- prep: grid = 128 pixel-blocks (one per (b,h)) + 72 B-pack blocks
__global__ __launch_bounds__(256) void smorph_prep(
    const float* __restrict__ x, const float* __restrict__ k1,
    const float* __restrict__ k2, float4* __restrict__ pixs,
    unsigned* __restrict__ pixm, unsigned short* __restrict__ bt)
{
    if (blockIdx.x < 128) {
        __shared__ float lmp[32*33], lmn[32*33], llp[32*33], lln[32*33];
        const int b = blockIdx.x >> 5, h = blockIdx.x & 31;
        const int tid = threadIdx.x;

#pragma unroll
        for (int i = 0; i < 4; ++i) {
            const int u = tid + 256*i;
            const int c = u >> 5, w = u & 31;
            float v = x[b*32768 + c*1024 + h*32 + w];
            float mp = fmaxf(v, 0.1f), mn = fmaxf(-v, 0.1f);
            lmp[c*33 + w] = mp;
            lmn[c*33 + w] = mn;
            llp[c*33 + w] = mp * __logf(mp);
            lln[c*33 + w] = mn * __logf(mn);
        }
        __syncthreads();

        const int pixbase = b*1024 + h*32;
#pragma unroll
        for (int i = 0; i < 8; ++i) {
            const int u    = tid + 256*i;         // w(5b) sign(1b) c(5b)
            const int c    = u & 31;
            const int sign = (u >> 5) & 1;
            const int w    = u >> 6;
            float m  = sign ? lmn[c*33 + w] : lmp[c*33 + w];
            float ml = sign ? lln[c*33 + w] : llp[c*33 + w];
            pixm[(pixbase + w)*64 + sign*32 + c] =
                (unsigned)f2bf(m) | ((unsigned)f2bf(ml) << 16);
        }

        if (tid < 64) {
            const int w  = tid & 31, hp = tid >> 5;
            float s0 = 0.f, s1 = 0.f, s2 = 0.f, s3 = 0.f;
#pragma unroll
            for (int cc = 0; cc < 16; ++cc) {
                const int c = hp*16 + cc;
                s0 += lmp[c*33 + w]; s1 += llp[c*33 + w];
                s2 += lmn[c*33 + w]; s3 += lln[c*33 + w];
            }
            s0 += __shfl_xor(s0, 32); s1 += __shfl_xor(s1, 32);
            s2 += __shfl_xor(s2, 32); s3 += __shfl_xor(s3, 32);
            if (hp == 0) pixs[pixbase + w] = make_float4(s0, s1, s2, s3);
        }
    } else {
        const int t = (blockIdx.x - 128)*256 + threadIdx.x;
        if (t < TB) {
            const int o = t & 63, p = t >> 6;
            const float a = k1[t], b2 = k2[t];
            const float d1 = expm1f(a),  q1 = a  * expf(a);
            const float d2 = expm1f(b2), q2 = b2 * expf(b2);
            const float vals[4][2] = {{d1, 0.f}, {q1, d1}, {d2, 0.f}, {q2, d2}};
#pragma unroll
            for (int tbl = 0; tbl < 4; ++tbl) {
                const int n = o*4 + tbl;
#pragma unroll
                for (int ks = 0; ks < 2; ++ks) {
                    const int k    = 2*p + ks;
                    const int st   = k >> 5, k32 = k & 31;
                    const int lane = (n & 15) + ((k32 >> 3) << 4);
                    bt[((n >> 4)*18 + st)*512 + lane*8 + (k32 & 7)] = f2bf(vals[tbl][ks]);
                }
            }
        }
    }
}

// ---- GEMM: 450 blocks x 256 thr (4 waves: kq x nhf). Wave: 32M x 64N x 9 steps.
__global__ __launch_bounds__(256, 2) void smorph_gemm(
    const unsigned* __restrict__ pixm, const unsigned short* __restrict__ bt,
    const float4* __restrict__ pixs, const float* __restrict__ bias,
    float* __restrict__ out)
{
    __shared__ float cmb[2][2048];               // 16 KB: K-combine, r-major
    __shared__ __align__(16) float epi[2][32*66];// 16.9 KB: epilogue transpose

    // ---- bijective XCD swizzle (m204): 450 blocks over 8 XCDs (450 = 8*56 + 2)
    int wgid;
    {
        const int orig = blockIdx.x;
        const int q = 450 / 8, rr = 450 % 8;     // q=56, rr=2
        const int xcd = orig % 8, idx = orig / 8;
        wgid = (xcd < rr ? xcd*(q+1) : rr*(q+1) + (xcd-rr)*q) + idx;
    }

    const int tid = threadIdx.x;
    const int l   = tid & 63;
    const int w   = tid >> 6;                  // wave 0..3
    const int kq  = w >> 1;                    // K-half (step parity)
    const int nhf = w & 1;                     // N-half within block
    const int bm  = wgid >> 1;                 // M-tile (16 s, 32 rows)
    const int nh  = wgid & 1;
    const int N0  = nh*128 + nhf*64;
    const int ng0 = N0 >> 4;

    const int lr = l & 15;
    const int lg = l >> 4;

    // ---- per-lane fp32 window sums (epilogue only)
    float4 S;
    {
        const int s  = bm*16 + lr;
        const int b  = s / NSP, r = s - b*NSP;
        const int ho = r / WO,  wo = r - WO*(r/WO);
        const float4* P = pixs + (b*1024 + ho*32 + wo);
        float4 a = make_float4(0,0,0,0);
#pragma unroll
        for (int kh = 0; kh < 3; ++kh)
#pragma unroll
            for (int kw = 0; kw < 3; ++kw) {
                float4 v = P[kh*32 + kw];
                a.x += v.x; a.y += v.y; a.z += v.z; a.w += v.w;
            }
        S = a;
    }

    // A lane byte-offsets into pixm: pix*256 + sign*128 + lg*16
    unsigned offA[2];
    {
        const int sign = lr & 1;
#pragma unroll
        for (int mi = 0; mi < 2; ++mi) {
            const int s  = bm*16 + mi*8 + (lr >> 1);
            const int b  = s / NSP, r = s - b*NSP;
            const int ho = r / WO,  wo = r - WO*(r/WO);
            const int pix = b*1024 + ho*32 + wo;
            offA[mi] = (unsigned)(pix*256 + sign*128 + lg*16);
        }
    }

    const char* pa = (const char*)pixm;
    const char* pb = (const char*)bt;

    f32x4 acc[2][4] = {};

#pragma unroll
    for (int s2 = 0; s2 < 9; ++s2) {
        const int step  = s2*2 + kq;           // this wave's 9 steps
        const int khkw  = step >> 1;
        const int kh    = khkw / 3, kw = khkw - 3*(khkw/3);
        const int khalf = step & 1;
        const unsigned immA = (unsigned)(kh*8192 + kw*256 + khalf*64);

        s16x8 a0 = *(const s16x8*)(pa + (offA[0] + immA));   // L2-hot, 16 lines
        s16x8 a1 = *(const s16x8*)(pa + (offA[1] + immA));
        s16x8 b0 = *(const s16x8*)(pb + (((ng0+0)*18 + step)*64 + l)*16);  // lane-linear
        s16x8 b1 = *(const s16x8*)(pb + (((ng0+1)*18 + step)*64 + l)*16);
        s16x8 b2 = *(const s16x8*)(pb + (((ng0+2)*18 + step)*64 + l)*16);
        s16x8 b3 = *(const s16x8*)(pb + (((ng0+3)*18 + step)*64 + l)*16);

        acc[0][0] = __builtin_amdgcn_mfma_f32_16x16x32_bf16(a0, b0, acc[0][0], 0, 0, 0);
        acc[0][1] = __builtin_amdgcn_mfma_f32_16x16x32_bf16(a0, b1, acc[0][1], 0, 0, 0);
        acc[0][2] = __builtin_amdgcn_mfma_f32_16x16x32_bf16(a0, b2, acc[0][2], 0, 0, 0);
        acc[0][3] = __builtin_amdgcn_mfma_f32_16x16x32_bf16(a0, b3, acc[0][3], 0, 0, 0);
        acc[1][0] = __builtin_amdgcn_mfma_f32_16x16x32_bf16(a1, b0, acc[1][0], 0, 0, 0);
        acc[1][1] = __builtin_amdgcn_mfma_f32_16x16x32_bf16(a1, b1, acc[1][1], 0, 0, 0);
        acc[1][2] = __builtin_amdgcn_mfma_f32_16x16x32_bf16(a1, b2, acc[1][2], 0, 0, 0);
        acc[1][3] = __builtin_amdgcn_mfma_f32_16x16x32_bf16(a1, b3, acc[1][3], 0, 0, 0);
    }

    // ---- K-combine: kq1 -> LDS (r-major, conflict-free), kq0 adds
    if (kq == 1) {
#pragma unroll
        for (int mi = 0; mi < 2; ++mi)
#pragma unroll
            for (int ni = 0; ni < 4; ++ni)
#pragma unroll
                for (int r = 0; r < 4; ++r)
                    cmb[nhf][(mi*16 + ni*4 + r)*64 + l] = acc[mi][ni][r];
    }
    __syncthreads();
    if (kq == 0) {
#pragma unroll
        for (int mi = 0; mi < 2; ++mi)
#pragma unroll
            for (int ni = 0; ni < 4; ++ni)
#pragma unroll
                for (int r = 0; r < 4; ++r)
                    acc[mi][ni][r] += cmb[nhf][(mi*16 + ni*4 + r)*64 + l];

        // epilogue write: acc -> epi[nhf] [row 0..31][col 0..63], pitch 66
        const int wrbase = lg*4*66 + lr;
#pragma unroll
        for (int mi = 0; mi < 2; ++mi)
#pragma unroll
            for (int ni = 0; ni < 4; ++ni)
#pragma unroll
                for (int r = 0; r < 4; ++r)
                    epi[nhf][wrbase + (mi*16 + r)*66 + ni*16] = acc[mi][ni][r];
    }
    __syncthreads();

    if (kq == 0) {
        const int sl = lr;
        const int s  = bm*16 + sl;
        const int b  = s / NSP;
        const int r900 = s - b*NSP;
#pragma unroll
        for (int oi = 0; oi < 4; ++oi) {
            int ol = lg*4 + oi;
            int o  = (N0 >> 2) + ol;
            float4 v0 = *(const float4*)&epi[nhf][(2*sl + 0)*66 + ol*4];  // pos
            float4 v1 = *(const float4*)&epi[nhf][(2*sl + 1)*66 + ol*4];  // neg
            float d1p = S.x + v0.x, n1p = S.y + v0.y;
            float d2p = S.x + v0.z, n2p = S.y + v0.w;
            float d1n = S.z + v1.x, n1n = S.w + v1.y;
            float d2n = S.z + v1.z, n2n = S.w + v1.w;
            float P = __expf(n1p/d1p) - __expf(n2p/d2p)
                    - __expf(n1n/d1n) + __expf(n2n/d2n);
            out[((size_t)(b*OO + o))*NSP + r900] = P + bias[o];
        }
    }
}

extern "C" void kernel_launch(void* const* d_in, const int* in_sizes, int n_in,
                              void* d_out, int out_size, void* d_ws, size_t ws_size,
                              hipStream_t stream) {
    const float* x    = (const float*)d_in[0];
    const float* k1   = (const float*)d_in[1];
    const float* k2   = (const float*)d_in[2];
    const float* bias = (const float*)d_in[3];

    char* ws = (char*)d_ws;
    float4*         pixs = (float4*)(ws);                    // 64 KB
    unsigned*       pixm = (unsigned*)(ws + 0x10000);        // 1 MB
    unsigned short* bt   = (unsigned short*)(ws + 0x110000); // 294,912 B
    float*          out  = (float*)d_out;

    hipLaunchKernelGGL(smorph_prep, dim3(128 + (TB + 255)/256), dim3(256), 0, stream,
                       x, k1, k2, pixs, pixm, bt);
    hipLaunchKernelGGL(smorph_gemm, dim3(450), dim3(256), 0, stream,
                       pixm, bt, pixs, bias, out);
}